// Round 3
// baseline (55.664 us; speedup 1.0000x reference)
//
#include <hip/hip_runtime.h>
#include <stdint.h>

// Problem constants
static constexpr int NB = 16;     // batch
static constexpr int CI = 32;     // in channels
static constexpr int CO = 64;     // out channels
static constexpr int HI = 224, WI = 224;
static constexpr int HO = 112, WO = 112;
static constexpr int HW = HI * WI;
static constexpr float EPS = 1e-5f;

typedef _Float16 h2 __attribute__((ext_vector_type(2)));

__device__ __forceinline__ h2 as_h2(uint32_t u) {
    union { uint32_t u; h2 h; } c; c.u = u; return c.h;
}
__device__ __forceinline__ uint32_t pack_h2(float a, float b) {
    union { uint32_t u; h2 h; } c;
    c.h = (h2){(_Float16)a, (_Float16)b};
    return c.u;
}

// Workspace layout (bytes): packed weights only.
static constexpr size_t OFF_WT2 = 3072;   // wbits: CO*12 u32 = 3072
static constexpr size_t OFF_A1  = 7168;   // wt2:   16*CO u32 = 4096
static constexpr size_t OFF_CC  = 7424;   // A1/Cc: CO f32 each
static constexpr size_t WS_NEED = 7680;

// Padded s_xb column index: breaks pg-stride-32B 4-way bank conflict, keeps
// every phase-2 uint4 read 16B-aligned (col 8*pg -> idx 12*pg).
__device__ __forceinline__ int XB(int c) { return c + ((c >> 3) << 2); }
static constexpr int XBW = 132 + ((132 / 8) << 2) + 4;   // 200 u32 per row

__global__ __launch_bounds__(256) void prep_kernel(
    const float* __restrict__ wbody,
    const float* __restrict__ g1, const float* __restrict__ b1,
    const float* __restrict__ m1, const float* __restrict__ v1,
    const float* __restrict__ wds,
    const float* __restrict__ g2, const float* __restrict__ b2,
    const float* __restrict__ m2, const float* __restrict__ v2,
    uint32_t* __restrict__ wbits, uint32_t* __restrict__ wt2,
    float* __restrict__ A1, float* __restrict__ Cc)
{
    int i = blockIdx.x * 256 + threadIdx.x;
    if (i < 16 * CO) {
        int ci2 = i >> 6, co = i & 63;
        float inv2 = g2[co] * rsqrtf(v2[co] + EPS);
        float w0 = wds[co * CI + 2 * ci2]     * inv2;
        float w1 = wds[co * CI + 2 * ci2 + 1] * inv2;
        wt2[i] = pack_h2(w0, w1);
    } else if (i < 16 * CO + CO * 9) {
        int j = i - 16 * CO;
        int co = j / 9, k = j % 9;
        uint32_t bits = 0u;
        for (int ci = 0; ci < CI; ++ci) {
            float wv = wbody[(co * CI + ci) * 9 + k];
            bits |= (uint32_t)(wv >= 0.0f) << ci;
        }
        wbits[co * 12 + k] = bits;
    } else if (i < 16 * CO + CO * 9 + CO) {
        int co = i - 16 * CO - CO * 9;
        float inv1 = g1[co] * rsqrtf(v1[co] + EPS);
        float inv2 = g2[co] * rsqrtf(v2[co] + EPS);
        A1[co] = -2.0f * inv1;
        Cc[co] = b1[co] - m1[co] * inv1 + b2[co] - m2[co] * inv2 + 288.0f * inv1;
    }
}

// Fused, software-pipelined kernel.
// Block = (b, row-quad gg -> output rows 4gg..4gg+3, 64-wide ow tile).
// Input rows ih0-1 .. ih0+7 (ih0 = 8gg) live in s_xb rows 0..8 (row 4 shared
// between the two halves). Schedule:
//   derive rows 0..4 (+avg rows 0..1) -> barrier
//   {issue loads half2-chunkA} compute r=0 {process A}
//   {issue loads chunkB+halo}  compute r=1 {process B, butterfly, store bits}
//   barrier -> compute r=2, r=3
__global__ __launch_bounds__(256) void fused_kernel(
    const float* __restrict__ x,
    const uint32_t* __restrict__ wbits, const uint32_t* __restrict__ wt2,
    const float* __restrict__ A1p, const float* __restrict__ Ccp,
    float* __restrict__ out)
{
    // XCD-chunked bijective swizzle: 896 = 8 * 112; consecutive gg same XCD.
    const int bid  = (blockIdx.x & 7) * 112 + (blockIdx.x >> 3);
    const int tile = bid & 1;
    const int gb   = bid >> 1;
    const int gg   = gb % 28;
    const int b    = gb / 28;
    const int ih0  = 8 * gg;           // abs input row of s_xb rel-row 1
    const int ow0  = tile * 64;
    const int t    = threadIdx.x;

    // LDS: 7200 + 17408 + 4096 + 3072 + 512 = 32,288 B
    __shared__ __align__(16) uint32_t s_xb[9][XBW];     // input rows ih0-1..ih0+7
    __shared__ __align__(16) uint32_t s_avg[4][16][68]; // out rows 4gg..4gg+3
    __shared__ __align__(16) uint32_t s_wt2[16][64];
    __shared__ __align__(16) uint32_t s_wb[CO * 12];
    __shared__ float s_A1[CO], s_C[CO];

    // ---------------- Phase 0: coalesced packed-weight staging ----------------
    {
        uint32_t* wt2s = (uint32_t*)s_wt2;
#pragma unroll
        for (int i = 0; i < 4; ++i) wt2s[t + 256 * i] = wt2[t + 256 * i];
#pragma unroll
        for (int i = 0; i < 3; ++i) s_wb[t + 256 * i] = wbits[t + 256 * i];
        if (t < CO) { s_A1[t] = A1p[t]; s_C[t] = Ccp[t]; }
    }

    // per-thread derive indexing (both halves)
    const int pair = t >> 7;        // 0..1
    const int q    = t & 3;         // ci quarter (ci = 8q..8q+7)
    const int f    = (t >> 2) & 31; // float4 col group: in-cols 2ow0+4f..+3
    const int jcol = 2 * ow0 + 4 * f;
    const bool colok = (jcol + 3 < WI);

    // ---------------- First derive: input rows rel 1..4, avg rows 0..1 -------
    {
        const float* xp = x + ((size_t)(b * CI + 8 * q) * HI + (ih0 + 2 * pair)) * WI + jcol;
        uint32_t m0[4] = {0, 0, 0, 0}, m1r[4] = {0, 0, 0, 0};
#pragma unroll
        for (int k = 0; k < 4; ++k) {
            const int c0 = 2 * k, c1 = c0 + 1;
            const int s0 = 8 * q + 2 * k, s1 = s0 + 1;
            float4 t0 = make_float4(0.f, 0.f, 0.f, 0.f);
            float4 u0 = t0, t1 = t0, u1 = t0;
            if (colok) {
                t0 = *(const float4*)(xp + (size_t)c0 * HW);
                u0 = *(const float4*)(xp + (size_t)c0 * HW + WI);
                t1 = *(const float4*)(xp + (size_t)c1 * HW);
                u1 = *(const float4*)(xp + (size_t)c1 * HW + WI);
            }
            m0[0]  |= ((uint32_t)(t0.x >= 0.f) << s0) | ((uint32_t)(t1.x >= 0.f) << s1);
            m0[1]  |= ((uint32_t)(t0.y >= 0.f) << s0) | ((uint32_t)(t1.y >= 0.f) << s1);
            m0[2]  |= ((uint32_t)(t0.z >= 0.f) << s0) | ((uint32_t)(t1.z >= 0.f) << s1);
            m0[3]  |= ((uint32_t)(t0.w >= 0.f) << s0) | ((uint32_t)(t1.w >= 0.f) << s1);
            m1r[0] |= ((uint32_t)(u0.x >= 0.f) << s0) | ((uint32_t)(u1.x >= 0.f) << s1);
            m1r[1] |= ((uint32_t)(u0.y >= 0.f) << s0) | ((uint32_t)(u1.y >= 0.f) << s1);
            m1r[2] |= ((uint32_t)(u0.z >= 0.f) << s0) | ((uint32_t)(u1.z >= 0.f) << s1);
            m1r[3] |= ((uint32_t)(u0.w >= 0.f) << s0) | ((uint32_t)(u1.w >= 0.f) << s1);
            float a0p0 = 0.25f * ((t0.x + t0.y) + (u0.x + u0.y));
            float a0p1 = 0.25f * ((t0.z + t0.w) + (u0.z + u0.w));
            float a1p0 = 0.25f * ((t1.x + t1.y) + (u1.x + u1.y));
            float a1p1 = 0.25f * ((t1.z + t1.w) + (u1.z + u1.w));
            *(uint2*)&s_avg[pair][4 * q + k][2 * f] =
                make_uint2(pack_h2(a0p0, a1p0), pack_h2(a0p1, a1p1));
        }
#pragma unroll
        for (int j = 0; j < 4; ++j) {
            m0[j]  |= __shfl_xor(m0[j], 1);  m0[j]  |= __shfl_xor(m0[j], 2);
            m1r[j] |= __shfl_xor(m1r[j], 1); m1r[j] |= __shfl_xor(m1r[j], 2);
        }
        uint32_t v0  = (q == 0) ? m0[0]  : (q == 1) ? m0[1]  : (q == 2) ? m0[2]  : m0[3];
        uint32_t v1v = (q == 0) ? m1r[0] : (q == 1) ? m1r[1] : (q == 2) ? m1r[2] : m1r[3];
        s_xb[1 + 2 * pair][XB(1 + 4 * f + q)] = v0;
        s_xb[2 + 2 * pair][XB(1 + 4 * f + q)] = v1v;
    }
    // Halo row (rel 0 = input ih0-1), threads 0..127.
    if (t < 128) {
        const int hq = t & 3, hf = t >> 2;
        const int hj = 2 * ow0 + 4 * hf;
        uint32_t mm[4] = {0, 0, 0, 0};
        if (gg > 0 && hj + 3 < WI) {
            const float* xp = x + ((size_t)(b * CI + 8 * hq) * HI + (ih0 - 1)) * WI + hj;
#pragma unroll
            for (int k = 0; k < 4; ++k) {
                const int s0 = 8 * hq + 2 * k, s1 = s0 + 1;
                const float4 t0 = *(const float4*)(xp + (size_t)(2 * k) * HW);
                const float4 t1 = *(const float4*)(xp + (size_t)(2 * k + 1) * HW);
                mm[0] |= ((uint32_t)(t0.x >= 0.f) << s0) | ((uint32_t)(t1.x >= 0.f) << s1);
                mm[1] |= ((uint32_t)(t0.y >= 0.f) << s0) | ((uint32_t)(t1.y >= 0.f) << s1);
                mm[2] |= ((uint32_t)(t0.z >= 0.f) << s0) | ((uint32_t)(t1.z >= 0.f) << s1);
                mm[3] |= ((uint32_t)(t0.w >= 0.f) << s0) | ((uint32_t)(t1.w >= 0.f) << s1);
            }
        }
#pragma unroll
        for (int j = 0; j < 4; ++j) { mm[j] |= __shfl_xor(mm[j], 1); mm[j] |= __shfl_xor(mm[j], 2); }
        s_xb[0][XB(1 + 4 * hf + hq)] = (hq == 0) ? mm[0] : (hq == 1) ? mm[1] : (hq == 2) ? mm[2] : mm[3];
    }
    // Halo column (c=0, in-col 2ow0-1) for rel rows 0..4.
    if (t < 40) {
        const int lr = t >> 3, l = t & 7;
        uint32_t bits = 0u;
        const int hr = ih0 - 1 + lr;
        const int wc = 2 * ow0 - 1;
        if (hr >= 0 && wc >= 0) {
            const float* xp = x + ((size_t)(b * CI + 4 * l) * HI + hr) * WI + wc;
#pragma unroll
            for (int ci = 0; ci < 4; ++ci)
                bits |= (uint32_t)(xp[(size_t)ci * HW] >= 0.0f) << (4 * l + ci);
        }
        bits |= __shfl_xor(bits, 1);
        bits |= __shfl_xor(bits, 2);
        bits |= __shfl_xor(bits, 4);
        if (l == 0) s_xb[lr][XB(0)] = bits;
    }
    __syncthreads();

    // ---------------- Compute machinery (proven body) ----------------
    const int cg  = t >> 4;
    const int pg  = t & 15;
    const int co0 = cg * 4;
    const int p0  = pg * 4;
    const bool pxvalid = (ow0 + p0 < WO);
    const bool px0 = (ow0 + p0 == 0);
    const int cb = 12 * pg;     // XB(8*pg)

    auto compute_row = [&](int r) {
        float fa[4][4] = {{0.f,0.f,0.f,0.f},{0.f,0.f,0.f,0.f},{0.f,0.f,0.f,0.f},{0.f,0.f,0.f,0.f}};
#pragma unroll 4
        for (int ci2 = 0; ci2 < 16; ++ci2) {
            uint4 av = *(const uint4*)&s_avg[r][ci2][p0];
            uint4 wv = *(const uint4*)&s_wt2[ci2][co0];
            h2 a[4] = {as_h2(av.x), as_h2(av.y), as_h2(av.z), as_h2(av.w)};
            h2 w[4] = {as_h2(wv.x), as_h2(wv.y), as_h2(wv.z), as_h2(wv.w)};
#pragma unroll
            for (int jc = 0; jc < 4; ++jc)
#pragma unroll
                for (int jp = 0; jp < 4; ++jp)
                    fa[jc][jp] = __builtin_amdgcn_fdot2(w[jc], a[jp], fa[jc][jp], false);
        }
        uint32_t xr[3][9];
#pragma unroll
        for (int rI = 0; rI < 3; ++rI) {
            const uint32_t* row = s_xb[2 * r + rI];
            uint4 a  = *(const uint4*)&row[cb];
            uint4 bq = *(const uint4*)&row[cb + 4];
            xr[rI][0] = a.x;  xr[rI][1] = a.y;  xr[rI][2] = a.z;  xr[rI][3] = a.w;
            xr[rI][4] = bq.x; xr[rI][5] = bq.y; xr[rI][6] = bq.z; xr[rI][7] = bq.w;
            xr[rI][8] = row[cb + 12];   // XB(8*pg + 8)
        }
        const bool ohf = (gg == 0 && r == 0);
        int sfin[4][4];
#pragma unroll
        for (int jc = 0; jc < 4; ++jc) {
            const int co = co0 + jc;
            uint4 wa  = *(const uint4*)&s_wb[co * 12];
            uint4 wb4 = *(const uint4*)&s_wb[co * 12 + 4];
            uint32_t wv[9] = {wa.x, wa.y, wa.z, wa.w, wb4.x, wb4.y, wb4.z, wb4.w,
                              s_wb[co * 12 + 8]};
#pragma unroll
            for (int jp = 0; jp < 4; ++jp) {
                int c00 = __popc(xr[0][2 * jp + 0] ^ wv[0]);
                int c01 = __popc(xr[0][2 * jp + 1] ^ wv[1]);
                int c02 = __popc(xr[0][2 * jp + 2] ^ wv[2]);
                int c10 = __popc(xr[1][2 * jp + 0] ^ wv[3]);
                int c11 = __popc(xr[1][2 * jp + 1] ^ wv[4]);
                int c12 = __popc(xr[1][2 * jp + 2] ^ wv[5]);
                int c20 = __popc(xr[2][2 * jp + 0] ^ wv[6]);
                int c21 = __popc(xr[2][2 * jp + 1] ^ wv[7]);
                int c22 = __popc(xr[2][2 * jp + 2] ^ wv[8]);
                int r0v  = c00 + c01 + c02;
                int ssum = r0v + c10 + c11 + c12 + c20 + c21 + c22;
                if (ohf) ssum += 48 - r0v;               // top image row
                if (px0 && jp == 0) {                    // left image column
                    ssum += 48 - (c00 + c10 + c20);
                    if (ohf) ssum += c00 - 16;           // corner double-fix
                }
                sfin[jc][jp] = ssum;
            }
        }
        if (pxvalid) {
#pragma unroll
            for (int jc = 0; jc < 4; ++jc) {
                const int co = co0 + jc;
                const float n2a = s_A1[co], cc = s_C[co];
                float4 o;
                o.x = fmaf(n2a, (float)sfin[jc][0], fa[jc][0] + cc);
                o.y = fmaf(n2a, (float)sfin[jc][1], fa[jc][1] + cc);
                o.z = fmaf(n2a, (float)sfin[jc][2], fa[jc][2] + cc);
                o.w = fmaf(n2a, (float)sfin[jc][3], fa[jc][3] + cc);
                *(float4*)&out[((size_t)(b * CO + co) * HO + (4 * gg + r)) * WO + ow0 + p0] = o;
            }
        }
    };

    // ---------------- Pipelined second derive (input rows rel 5..8) ----------
    const float* xp2 = x + ((size_t)(b * CI + 8 * q) * HI + (ih0 + 4 + 2 * pair)) * WI + jcol;
    uint32_t n0[4] = {0, 0, 0, 0}, n1[4] = {0, 0, 0, 0};

    auto proc_k = [&](int k, const float4& t0, const float4& u0,
                      const float4& t1, const float4& u1) {
        const int s0 = 8 * q + 2 * k, s1 = s0 + 1;
        n0[0] |= ((uint32_t)(t0.x >= 0.f) << s0) | ((uint32_t)(t1.x >= 0.f) << s1);
        n0[1] |= ((uint32_t)(t0.y >= 0.f) << s0) | ((uint32_t)(t1.y >= 0.f) << s1);
        n0[2] |= ((uint32_t)(t0.z >= 0.f) << s0) | ((uint32_t)(t1.z >= 0.f) << s1);
        n0[3] |= ((uint32_t)(t0.w >= 0.f) << s0) | ((uint32_t)(t1.w >= 0.f) << s1);
        n1[0] |= ((uint32_t)(u0.x >= 0.f) << s0) | ((uint32_t)(u1.x >= 0.f) << s1);
        n1[1] |= ((uint32_t)(u0.y >= 0.f) << s0) | ((uint32_t)(u1.y >= 0.f) << s1);
        n1[2] |= ((uint32_t)(u0.z >= 0.f) << s0) | ((uint32_t)(u1.z >= 0.f) << s1);
        n1[3] |= ((uint32_t)(u0.w >= 0.f) << s0) | ((uint32_t)(u1.w >= 0.f) << s1);
        float a0p0 = 0.25f * ((t0.x + t0.y) + (u0.x + u0.y));
        float a0p1 = 0.25f * ((t0.z + t0.w) + (u0.z + u0.w));
        float a1p0 = 0.25f * ((t1.x + t1.y) + (u1.x + u1.y));
        float a1p1 = 0.25f * ((t1.z + t1.w) + (u1.z + u1.w));
        *(uint2*)&s_avg[2 + pair][4 * q + k][2 * f] =
            make_uint2(pack_h2(a0p0, a1p0), pack_h2(a0p1, a1p1));
    };

    // chunk A loads (k = 0,1)
    float4 cA[8];
#pragma unroll
    for (int k = 0; k < 2; ++k) {
        float4 z = make_float4(0.f, 0.f, 0.f, 0.f);
        cA[4*k] = z; cA[4*k+1] = z; cA[4*k+2] = z; cA[4*k+3] = z;
        if (colok) {
            cA[4*k+0] = *(const float4*)(xp2 + (size_t)(2 * k) * HW);
            cA[4*k+1] = *(const float4*)(xp2 + (size_t)(2 * k) * HW + WI);
            cA[4*k+2] = *(const float4*)(xp2 + (size_t)(2 * k + 1) * HW);
            cA[4*k+3] = *(const float4*)(xp2 + (size_t)(2 * k + 1) * HW + WI);
        }
    }

    compute_row(0);          // loads of chunk A in flight underneath

    proc_k(0, cA[0], cA[1], cA[2], cA[3]);
    proc_k(1, cA[4], cA[5], cA[6], cA[7]);

    // chunk B loads (k = 2,3) + halo-col loads for rel rows 5..8
    float4 cB[8];
#pragma unroll
    for (int k = 0; k < 2; ++k) {
        float4 z = make_float4(0.f, 0.f, 0.f, 0.f);
        cB[4*k] = z; cB[4*k+1] = z; cB[4*k+2] = z; cB[4*k+3] = z;
        if (colok) {
            cB[4*k+0] = *(const float4*)(xp2 + (size_t)(2 * k + 4) * HW);
            cB[4*k+1] = *(const float4*)(xp2 + (size_t)(2 * k + 4) * HW + WI);
            cB[4*k+2] = *(const float4*)(xp2 + (size_t)(2 * k + 5) * HW);
            cB[4*k+3] = *(const float4*)(xp2 + (size_t)(2 * k + 5) * HW + WI);
        }
    }
    float hv[4] = {1.f, 1.f, 1.f, 1.f};
    const int wc = 2 * ow0 - 1;
    if (t < 32 && wc >= 0) {
        const int lr = t >> 3, l = t & 7;
        const float* xp = x + ((size_t)(b * CI + 4 * l) * HI + (ih0 + 4 + lr)) * WI + wc;
#pragma unroll
        for (int ci = 0; ci < 4; ++ci) hv[ci] = xp[(size_t)ci * HW];
    }

    compute_row(1);          // loads of chunk B in flight underneath

    proc_k(2, cB[0], cB[1], cB[2], cB[3]);
    proc_k(3, cB[4], cB[5], cB[6], cB[7]);
#pragma unroll
    for (int j = 0; j < 4; ++j) {
        n0[j] |= __shfl_xor(n0[j], 1); n0[j] |= __shfl_xor(n0[j], 2);
        n1[j] |= __shfl_xor(n1[j], 1); n1[j] |= __shfl_xor(n1[j], 2);
    }
    {
        uint32_t v0  = (q == 0) ? n0[0] : (q == 1) ? n0[1] : (q == 2) ? n0[2] : n0[3];
        uint32_t v1v = (q == 0) ? n1[0] : (q == 1) ? n1[1] : (q == 2) ? n1[2] : n1[3];
        s_xb[5 + 2 * pair][XB(1 + 4 * f + q)] = v0;
        s_xb[6 + 2 * pair][XB(1 + 4 * f + q)] = v1v;
    }
    if (t < 32) {
        const int lr = t >> 3, l = t & 7;
        uint32_t bits = 0u;
        if (wc >= 0) {
#pragma unroll
            for (int ci = 0; ci < 4; ++ci)
                bits |= (uint32_t)(hv[ci] >= 0.0f) << (4 * l + ci);
        }
        bits |= __shfl_xor(bits, 1);
        bits |= __shfl_xor(bits, 2);
        bits |= __shfl_xor(bits, 4);
        if (l == 0) s_xb[5 + lr][XB(0)] = bits;
    }
    __syncthreads();

    compute_row(2);
    compute_row(3);
}

// Fallback if workspace is too small: direct per-output computation (slow, correct).
__global__ __launch_bounds__(256) void naive_kernel(
    const float* __restrict__ x, const float* __restrict__ wbody,
    const float* __restrict__ g1, const float* __restrict__ b1,
    const float* __restrict__ m1, const float* __restrict__ v1,
    const float* __restrict__ wds,
    const float* __restrict__ g2, const float* __restrict__ b2,
    const float* __restrict__ m2, const float* __restrict__ v2,
    float* __restrict__ out)
{
    int i = blockIdx.x * 256 + threadIdx.x;
    if (i >= NB * CO * HO * WO) return;
    int ow = i % WO;
    int oh = (i / WO) % HO;
    int co = (i / (WO * HO)) % CO;
    int b  = i / (WO * HO * CO);
    float inv1 = g1[co] * rsqrtf(v1[co] + EPS);
    float inv2 = g2[co] * rsqrtf(v2[co] + EPS);
    int body = 0;
    float ds = 0.f;
    for (int ci = 0; ci < CI; ++ci) {
        const float* xp = x + (size_t)(b * CI + ci) * HW;
        for (int kh = 0; kh < 3; ++kh) {
            int hh = 2 * oh - 1 + kh;
            if (hh < 0 || hh >= HI) continue;
            for (int kw = 0; kw < 3; ++kw) {
                int ww = 2 * ow - 1 + kw;
                if (ww < 0 || ww >= WI) continue;
                float xv = xp[(size_t)hh * WI + ww];
                float wv = wbody[((co * CI + ci) * 3 + kh) * 3 + kw];
                int sx = (xv >= 0.f) ? 1 : -1;
                int sw = (wv >= 0.f) ? 1 : -1;
                body += sx * sw;
            }
        }
        float a = 0.25f * (xp[(size_t)(2 * oh) * WI + 2 * ow]
                         + xp[(size_t)(2 * oh) * WI + 2 * ow + 1]
                         + xp[(size_t)(2 * oh + 1) * WI + 2 * ow]
                         + xp[(size_t)(2 * oh + 1) * WI + 2 * ow + 1]);
        ds += a * wds[co * CI + ci];
    }
    out[i] = inv1 * (float)body + (b1[co] - m1[co] * inv1)
           + inv2 * ds + (b2[co] - m2[co] * inv2);
}

extern "C" void kernel_launch(void* const* d_in, const int* in_sizes, int n_in,
                              void* d_out, int out_size, void* d_ws, size_t ws_size,
                              hipStream_t stream)
{
    (void)in_sizes; (void)n_in; (void)out_size;
    const float* x   = (const float*)d_in[0];
    const float* wbd = (const float*)d_in[1];
    const float* g1  = (const float*)d_in[2];
    const float* b1  = (const float*)d_in[3];
    const float* m1  = (const float*)d_in[4];
    const float* v1  = (const float*)d_in[5];
    const float* wds = (const float*)d_in[6];
    const float* g2  = (const float*)d_in[7];
    const float* b2  = (const float*)d_in[8];
    const float* m2  = (const float*)d_in[9];
    const float* v2  = (const float*)d_in[10];
    float* out = (float*)d_out;

    if (ws_size < WS_NEED) {
        int total = NB * CO * HO * WO;
        naive_kernel<<<(total + 255) / 256, 256, 0, stream>>>(
            x, wbd, g1, b1, m1, v1, wds, g2, b2, m2, v2, out);
        return;
    }

    char* wsb = (char*)d_ws;
    uint32_t* wbits = (uint32_t*)wsb;
    uint32_t* wt2   = (uint32_t*)(wsb + OFF_WT2);
    float*    A1    = (float*)(wsb + OFF_A1);
    float*    Cc    = (float*)(wsb + OFF_CC);

    prep_kernel<<<7, 256, 0, stream>>>(wbd, g1, b1, m1, v1, wds, g2, b2, m2, v2,
                                       wbits, wt2, A1, Cc);
    // grid = NB * 28 row-quad groups * 2 ow tiles = 896 blocks (= 8 * 112)
    fused_kernel<<<dim3(NB * 28 * 2), 256, 0, stream>>>(
        x, wbits, wt2, A1, Cc, out);
}

// Round 4
// 47.792 us; speedup vs baseline: 1.1647x; 1.1647x over previous
//
#include <hip/hip_runtime.h>
#include <stdint.h>

// Problem constants
static constexpr int NB = 16;     // batch
static constexpr int CI = 32;     // in channels
static constexpr int CO = 64;     // out channels
static constexpr int HI = 224, WI = 224;
static constexpr int HO = 112, WO = 112;
static constexpr int HW = HI * WI;
static constexpr float EPS = 1e-5f;

typedef _Float16 h2 __attribute__((ext_vector_type(2)));

__device__ __forceinline__ h2 as_h2(uint32_t u) {
    union { uint32_t u; h2 h; } c; c.u = u; return c.h;
}
__device__ __forceinline__ uint32_t pack_h2(float a, float b) {
    union { uint32_t u; h2 h; } c;
    c.h = (h2){(_Float16)a, (_Float16)b};
    return c.u;
}

// Workspace layout (bytes): packed weights only.
static constexpr size_t OFF_WT2 = 3072;   // wbits: CO*12 u32 = 3072
static constexpr size_t OFF_A1  = 7168;   // wt2:   16*CO u32 = 4096
static constexpr size_t OFF_CC  = 7424;   // A1/Cc: CO f32 each
static constexpr size_t WS_NEED = 7680;

// Padded s_xb column index: breaks pg-stride-32B 4-way bank conflict, keeps
// every phase-2 uint4 read 16B-aligned (col 8*pg -> idx 12*pg).
__device__ __forceinline__ int XB(int c) { return c + ((c >> 3) << 2); }
static constexpr int XBW = 132 + ((132 / 8) << 2) + 4;   // 200 u32 per row

__global__ __launch_bounds__(256) void prep_kernel(
    const float* __restrict__ wbody,
    const float* __restrict__ g1, const float* __restrict__ b1,
    const float* __restrict__ m1, const float* __restrict__ v1,
    const float* __restrict__ wds,
    const float* __restrict__ g2, const float* __restrict__ b2,
    const float* __restrict__ m2, const float* __restrict__ v2,
    uint32_t* __restrict__ wbits, uint32_t* __restrict__ wt2,
    float* __restrict__ A1, float* __restrict__ Cc)
{
    int i = blockIdx.x * 256 + threadIdx.x;
    if (i < 16 * CO) {
        int ci2 = i >> 6, co = i & 63;
        float inv2 = g2[co] * rsqrtf(v2[co] + EPS);
        float w0 = wds[co * CI + 2 * ci2]     * inv2;
        float w1 = wds[co * CI + 2 * ci2 + 1] * inv2;
        wt2[i] = pack_h2(w0, w1);
    } else if (i < 16 * CO + CO * 9) {
        int j = i - 16 * CO;
        int co = j / 9, k = j % 9;
        uint32_t bits = 0u;
#pragma unroll
        for (int ci = 0; ci < CI; ++ci) {
            float wv = wbody[(co * CI + ci) * 9 + k];
            bits |= (uint32_t)(wv >= 0.0f) << ci;
        }
        wbits[co * 12 + k] = bits;
    } else if (i < 16 * CO + CO * 9 + CO) {
        int co = i - 16 * CO - CO * 9;
        float inv1 = g1[co] * rsqrtf(v1[co] + EPS);
        float inv2 = g2[co] * rsqrtf(v2[co] + EPS);
        A1[co] = -2.0f * inv1;
        Cc[co] = b1[co] - m1[co] * inv1 + b2[co] - m2[co] * inv2 + 288.0f * inv1;
    }
}

// Fused derive+compute kernel, round-2 structure (2 output rows / block,
// 1792 blocks) with a single-burst load schedule: ALL global loads (weights,
// 16 main float4, 8 halo-row float4, 4 halo-col scalars) issue before any
// processing, so each wave pays ~one memory-latency exposure instead of ~6.
__global__ __launch_bounds__(256) void fused_kernel(
    const float* __restrict__ x,
    const uint32_t* __restrict__ wbits, const uint32_t* __restrict__ wt2,
    const float* __restrict__ A1p, const float* __restrict__ Ccp,
    float* __restrict__ out)
{
    // XCD-chunked bijective swizzle: 1792 = 8 * 224.
    const int bid  = (blockIdx.x & 7) * 224 + (blockIdx.x >> 3);
    const int tile = bid & 1;
    const int gb   = bid >> 1;
    const int g    = gb % 56;          // row-pair group: output rows 2g, 2g+1
    const int b    = gb / 56;
    const int oh0  = 2 * g;
    const int ow0  = tile * 64;
    const int t    = threadIdx.x;

    // LDS: 4000 + 8704 + 4096 + 3072 + 512 = 20,384 B -> 8 blocks/CU LDS-limit
    __shared__ __align__(16) uint32_t s_xb[5][XBW];     // rows rel -1..3, padded cols
    __shared__ __align__(16) uint32_t s_avg[2][16][68]; // [out-row r][ci2][local ow]
    __shared__ __align__(16) uint32_t s_wt2[16][64];
    __shared__ __align__(16) uint32_t s_wb[CO * 12];
    __shared__ float s_A1[CO], s_C[CO];

    // ---- Burst 0: weight loads (oldest in vmcnt FIFO, complete first) ----
    uint32_t wtv[4], wbv[3];
    float a1v = 0.f, ccv = 0.f;
#pragma unroll
    for (int i = 0; i < 4; ++i) wtv[i] = wt2[t + 256 * i];
#pragma unroll
    for (int i = 0; i < 3; ++i) wbv[i] = wbits[t + 256 * i];
    if (t < CO) { a1v = A1p[t]; ccv = Ccp[t]; }

    // per-thread derive indexing
    const int pair = t >> 7;        // 0..1 -> input rows 2oh0+2pair, +1
    const int q    = t & 3;         // ci quarter (ci = 8q..8q+7)
    const int f    = (t >> 2) & 31; // float4 col group: in-cols 2ow0+4f..+3
    const int jcol = 2 * ow0 + 4 * f;
    const bool colok = (jcol + 3 < WI);

    // ---- Burst 1: 16 main-row float4 loads ----
    const float* xp = x + ((size_t)(b * CI + 8 * q) * HI + (oh0 * 2 + 2 * pair)) * WI + jcol;
    float4 L[16];
#pragma unroll
    for (int i = 0; i < 16; ++i) L[i] = make_float4(0.f, 0.f, 0.f, 0.f);
    if (colok) {
#pragma unroll
        for (int k = 0; k < 4; ++k) {
            L[4 * k + 0] = *(const float4*)(xp + (size_t)(2 * k) * HW);
            L[4 * k + 1] = *(const float4*)(xp + (size_t)(2 * k) * HW + WI);
            L[4 * k + 2] = *(const float4*)(xp + (size_t)(2 * k + 1) * HW);
            L[4 * k + 3] = *(const float4*)(xp + (size_t)(2 * k + 1) * HW + WI);
        }
    }

    // ---- Burst 2: 8 halo-row float4 loads (threads 0..127; q,f same as main) ----
    float4 H[8];
#pragma unroll
    for (int i = 0; i < 8; ++i) H[i] = make_float4(0.f, 0.f, 0.f, 0.f);
    if (t < 128 && g > 0 && colok) {
        const float* xh = x + ((size_t)(b * CI + 8 * q) * HI + (oh0 * 2 - 1)) * WI + jcol;
#pragma unroll
        for (int k = 0; k < 8; ++k)
            H[k] = *(const float4*)(xh + (size_t)k * HW);
    }

    // ---- Burst 3: 4 halo-col scalar loads (threads 0..39) ----
    const int wc = 2 * ow0 - 1;
    float hv[4] = {-1.f, -1.f, -1.f, -1.f};
    const int lr = t >> 3, lch = t & 7;          // only meaningful for t<40
    const int hr = oh0 * 2 - 1 + lr;
    if (t < 40 && hr >= 0 && wc >= 0) {
        const float* xc = x + ((size_t)(b * CI + 4 * lch) * HI + hr) * WI + wc;
#pragma unroll
        for (int ci = 0; ci < 4; ++ci) hv[ci] = xc[(size_t)ci * HW];
    }

    // ---- Store weights to LDS (waits only on burst-0 FIFO entries) ----
    {
        uint32_t* wt2s = (uint32_t*)s_wt2;
#pragma unroll
        for (int i = 0; i < 4; ++i) wt2s[t + 256 * i] = wtv[i];
#pragma unroll
        for (int i = 0; i < 3; ++i) s_wb[t + 256 * i] = wbv[i];
        if (t < CO) { s_A1[t] = a1v; s_C[t] = ccv; }
    }

    // ---- Process main rows (bits + avgpool) ----
    {
        uint32_t m0[4] = {0, 0, 0, 0}, m1r[4] = {0, 0, 0, 0};
#pragma unroll
        for (int k = 0; k < 4; ++k) {
            const float4 t0 = L[4 * k + 0], u0 = L[4 * k + 1];
            const float4 t1 = L[4 * k + 2], u1 = L[4 * k + 3];
            const int s0 = 8 * q + 2 * k, s1 = s0 + 1;
            m0[0]  |= ((uint32_t)(t0.x >= 0.f) << s0) | ((uint32_t)(t1.x >= 0.f) << s1);
            m0[1]  |= ((uint32_t)(t0.y >= 0.f) << s0) | ((uint32_t)(t1.y >= 0.f) << s1);
            m0[2]  |= ((uint32_t)(t0.z >= 0.f) << s0) | ((uint32_t)(t1.z >= 0.f) << s1);
            m0[3]  |= ((uint32_t)(t0.w >= 0.f) << s0) | ((uint32_t)(t1.w >= 0.f) << s1);
            m1r[0] |= ((uint32_t)(u0.x >= 0.f) << s0) | ((uint32_t)(u1.x >= 0.f) << s1);
            m1r[1] |= ((uint32_t)(u0.y >= 0.f) << s0) | ((uint32_t)(u1.y >= 0.f) << s1);
            m1r[2] |= ((uint32_t)(u0.z >= 0.f) << s0) | ((uint32_t)(u1.z >= 0.f) << s1);
            m1r[3] |= ((uint32_t)(u0.w >= 0.f) << s0) | ((uint32_t)(u1.w >= 0.f) << s1);
            float a0p0 = 0.25f * ((t0.x + t0.y) + (u0.x + u0.y));
            float a0p1 = 0.25f * ((t0.z + t0.w) + (u0.z + u0.w));
            float a1p0 = 0.25f * ((t1.x + t1.y) + (u1.x + u1.y));
            float a1p1 = 0.25f * ((t1.z + t1.w) + (u1.z + u1.w));
            *(uint2*)&s_avg[pair][4 * q + k][2 * f] =
                make_uint2(pack_h2(a0p0, a1p0), pack_h2(a0p1, a1p1));
        }
#pragma unroll
        for (int j = 0; j < 4; ++j) {
            m0[j]  |= __shfl_xor(m0[j], 1);  m0[j]  |= __shfl_xor(m0[j], 2);
            m1r[j] |= __shfl_xor(m1r[j], 1); m1r[j] |= __shfl_xor(m1r[j], 2);
        }
        uint32_t v0  = (q == 0) ? m0[0]  : (q == 1) ? m0[1]  : (q == 2) ? m0[2]  : m0[3];
        uint32_t v1v = (q == 0) ? m1r[0] : (q == 1) ? m1r[1] : (q == 2) ? m1r[2] : m1r[3];
        s_xb[1 + 2 * pair][XB(1 + 4 * f + q)] = v0;
        s_xb[2 + 2 * pair][XB(1 + 4 * f + q)] = v1v;
    }

    // ---- Process halo row (threads 0..127) ----
    if (t < 128) {
        uint32_t mm[4] = {0, 0, 0, 0};
#pragma unroll
        for (int k = 0; k < 4; ++k) {
            const float4 t0 = H[2 * k], t1 = H[2 * k + 1];
            const int s0 = 8 * q + 2 * k, s1 = s0 + 1;
            mm[0] |= ((uint32_t)(t0.x >= 0.f) << s0) | ((uint32_t)(t1.x >= 0.f) << s1);
            mm[1] |= ((uint32_t)(t0.y >= 0.f) << s0) | ((uint32_t)(t1.y >= 0.f) << s1);
            mm[2] |= ((uint32_t)(t0.z >= 0.f) << s0) | ((uint32_t)(t1.z >= 0.f) << s1);
            mm[3] |= ((uint32_t)(t0.w >= 0.f) << s0) | ((uint32_t)(t1.w >= 0.f) << s1);
        }
        // if g==0 or !colok H stayed zero -> bits would be garbage(=1 for 0.0f>=0);
        // must force 0 exactly as round 2 (bits stored 0 when out of image).
        if (!(g > 0 && colok)) { mm[0] = mm[1] = mm[2] = mm[3] = 0u; }
#pragma unroll
        for (int j = 0; j < 4; ++j) { mm[j] |= __shfl_xor(mm[j], 1); mm[j] |= __shfl_xor(mm[j], 2); }
        s_xb[0][XB(1 + 4 * f + q)] = (q == 0) ? mm[0] : (q == 1) ? mm[1] : (q == 2) ? mm[2] : mm[3];
    }
    // ---- Process halo column (threads 0..39) ----
    if (t < 40) {
        uint32_t bits = 0u;
        if (hr >= 0 && wc >= 0) {
#pragma unroll
            for (int ci = 0; ci < 4; ++ci)
                bits |= (uint32_t)(hv[ci] >= 0.0f) << (4 * lch + ci);
        }
        bits |= __shfl_xor(bits, 1);
        bits |= __shfl_xor(bits, 2);
        bits |= __shfl_xor(bits, 4);
        if (lch == 0) s_xb[lr][XB(0)] = bits;
    }
    __syncthreads();

    // ---------------- Phase 2: compute (proven main_kernel body) ----------------
    const int cg  = t >> 4;     // 16 co-groups
    const int pg  = t & 15;     // 16 pixel-groups
    const int co0 = cg * 4;
    const int p0  = pg * 4;
    const bool pxvalid = (ow0 + p0 < WO);
    const bool px0 = (ow0 + p0 == 0);
    const int cb = 12 * pg;     // XB(8*pg)

#pragma unroll 1
    for (int r = 0; r < 2; ++r) {
        // Downsample branch: 4co x 4pix dot2 tile over 16 ci-pairs
        float fa[4][4] = {{0.f,0.f,0.f,0.f},{0.f,0.f,0.f,0.f},{0.f,0.f,0.f,0.f},{0.f,0.f,0.f,0.f}};
#pragma unroll 4
        for (int ci2 = 0; ci2 < 16; ++ci2) {
            uint4 av = *(const uint4*)&s_avg[r][ci2][p0];
            uint4 wv = *(const uint4*)&s_wt2[ci2][co0];
            h2 a[4] = {as_h2(av.x), as_h2(av.y), as_h2(av.z), as_h2(av.w)};
            h2 w[4] = {as_h2(wv.x), as_h2(wv.y), as_h2(wv.z), as_h2(wv.w)};
#pragma unroll
            for (int jc = 0; jc < 4; ++jc)
#pragma unroll
                for (int jp = 0; jp < 4; ++jp)
                    fa[jc][jp] = __builtin_amdgcn_fdot2(w[jc], a[jp], fa[jc][jp], false);
        }

        // Body branch: taps c = 8*pg + 2*jp + kw -> padded idx cb + 2*jp + kw
        uint32_t xr[3][9];
#pragma unroll
        for (int rI = 0; rI < 3; ++rI) {
            const uint32_t* row = s_xb[2 * r + rI];
            uint4 a  = *(const uint4*)&row[cb];
            uint4 bq = *(const uint4*)&row[cb + 4];
            xr[rI][0] = a.x;  xr[rI][1] = a.y;  xr[rI][2] = a.z;  xr[rI][3] = a.w;
            xr[rI][4] = bq.x; xr[rI][5] = bq.y; xr[rI][6] = bq.z; xr[rI][7] = bq.w;
            xr[rI][8] = row[cb + 12];   // XB(8*pg + 8)
        }

        const bool ohf = (g == 0 && r == 0);
        int sfin[4][4];
#pragma unroll
        for (int jc = 0; jc < 4; ++jc) {
            const int co = co0 + jc;
            uint4 wa  = *(const uint4*)&s_wb[co * 12];
            uint4 wb4 = *(const uint4*)&s_wb[co * 12 + 4];
            uint32_t wv[9] = {wa.x, wa.y, wa.z, wa.w, wb4.x, wb4.y, wb4.z, wb4.w,
                              s_wb[co * 12 + 8]};
#pragma unroll
            for (int jp = 0; jp < 4; ++jp) {
                int c00 = __popc(xr[0][2 * jp + 0] ^ wv[0]);
                int c01 = __popc(xr[0][2 * jp + 1] ^ wv[1]);
                int c02 = __popc(xr[0][2 * jp + 2] ^ wv[2]);
                int c10 = __popc(xr[1][2 * jp + 0] ^ wv[3]);
                int c11 = __popc(xr[1][2 * jp + 1] ^ wv[4]);
                int c12 = __popc(xr[1][2 * jp + 2] ^ wv[5]);
                int c20 = __popc(xr[2][2 * jp + 0] ^ wv[6]);
                int c21 = __popc(xr[2][2 * jp + 1] ^ wv[7]);
                int c22 = __popc(xr[2][2 * jp + 2] ^ wv[8]);
                int r0v  = c00 + c01 + c02;
                int ssum = r0v + c10 + c11 + c12 + c20 + c21 + c22;
                if (ohf) ssum += 48 - r0v;               // top image row
                if (px0 && jp == 0) {                    // left image column
                    ssum += 48 - (c00 + c10 + c20);
                    if (ohf) ssum += c00 - 16;           // corner double-fix
                }
                sfin[jc][jp] = ssum;
            }
        }

        if (pxvalid) {
#pragma unroll
            for (int jc = 0; jc < 4; ++jc) {
                const int co = co0 + jc;
                const float n2a = s_A1[co], cc = s_C[co];
                float4 o;
                o.x = fmaf(n2a, (float)sfin[jc][0], fa[jc][0] + cc);
                o.y = fmaf(n2a, (float)sfin[jc][1], fa[jc][1] + cc);
                o.z = fmaf(n2a, (float)sfin[jc][2], fa[jc][2] + cc);
                o.w = fmaf(n2a, (float)sfin[jc][3], fa[jc][3] + cc);
                *(float4*)&out[((size_t)(b * CO + co) * HO + (oh0 + r)) * WO + ow0 + p0] = o;
            }
        }
    }
}

// Fallback if workspace is too small: direct per-output computation (slow, correct).
__global__ __launch_bounds__(256) void naive_kernel(
    const float* __restrict__ x, const float* __restrict__ wbody,
    const float* __restrict__ g1, const float* __restrict__ b1,
    const float* __restrict__ m1, const float* __restrict__ v1,
    const float* __restrict__ wds,
    const float* __restrict__ g2, const float* __restrict__ b2,
    const float* __restrict__ m2, const float* __restrict__ v2,
    float* __restrict__ out)
{
    int i = blockIdx.x * 256 + threadIdx.x;
    if (i >= NB * CO * HO * WO) return;
    int ow = i % WO;
    int oh = (i / WO) % HO;
    int co = (i / (WO * HO)) % CO;
    int b  = i / (WO * HO * CO);
    float inv1 = g1[co] * rsqrtf(v1[co] + EPS);
    float inv2 = g2[co] * rsqrtf(v2[co] + EPS);
    int body = 0;
    float ds = 0.f;
    for (int ci = 0; ci < CI; ++ci) {
        const float* xp = x + (size_t)(b * CI + ci) * HW;
        for (int kh = 0; kh < 3; ++kh) {
            int hh = 2 * oh - 1 + kh;
            if (hh < 0 || hh >= HI) continue;
            for (int kw = 0; kw < 3; ++kw) {
                int ww = 2 * ow - 1 + kw;
                if (ww < 0 || ww >= WI) continue;
                float xv = xp[(size_t)hh * WI + ww];
                float wv = wbody[((co * CI + ci) * 3 + kh) * 3 + kw];
                int sx = (xv >= 0.f) ? 1 : -1;
                int sw = (wv >= 0.f) ? 1 : -1;
                body += sx * sw;
            }
        }
        float a = 0.25f * (xp[(size_t)(2 * oh) * WI + 2 * ow]
                         + xp[(size_t)(2 * oh) * WI + 2 * ow + 1]
                         + xp[(size_t)(2 * oh + 1) * WI + 2 * ow]
                         + xp[(size_t)(2 * oh + 1) * WI + 2 * ow + 1]);
        ds += a * wds[co * CI + ci];
    }
    out[i] = inv1 * (float)body + (b1[co] - m1[co] * inv1)
           + inv2 * ds + (b2[co] - m2[co] * inv2);
}

extern "C" void kernel_launch(void* const* d_in, const int* in_sizes, int n_in,
                              void* d_out, int out_size, void* d_ws, size_t ws_size,
                              hipStream_t stream)
{
    (void)in_sizes; (void)n_in; (void)out_size;
    const float* x   = (const float*)d_in[0];
    const float* wbd = (const float*)d_in[1];
    const float* g1  = (const float*)d_in[2];
    const float* b1  = (const float*)d_in[3];
    const float* m1  = (const float*)d_in[4];
    const float* v1  = (const float*)d_in[5];
    const float* wds = (const float*)d_in[6];
    const float* g2  = (const float*)d_in[7];
    const float* b2  = (const float*)d_in[8];
    const float* m2  = (const float*)d_in[9];
    const float* v2  = (const float*)d_in[10];
    float* out = (float*)d_out;

    if (ws_size < WS_NEED) {
        int total = NB * CO * HO * WO;
        naive_kernel<<<(total + 255) / 256, 256, 0, stream>>>(
            x, wbd, g1, b1, m1, v1, wds, g2, b2, m2, v2, out);
        return;
    }

    char* wsb = (char*)d_ws;
    uint32_t* wbits = (uint32_t*)wsb;
    uint32_t* wt2   = (uint32_t*)(wsb + OFF_WT2);
    float*    A1    = (float*)(wsb + OFF_A1);
    float*    Cc    = (float*)(wsb + OFF_CC);

    prep_kernel<<<7, 256, 0, stream>>>(wbd, g1, b1, m1, v1, wds, g2, b2, m2, v2,
                                       wbits, wt2, A1, Cc);
    // grid = NB * 56 row-pair groups * 2 ow tiles = 1792 blocks (= 8 * 224)
    fused_kernel<<<dim3(NB * 56 * 2), 256, 0, stream>>>(
        x, wbits, wt2, A1, Cc, out);
}